// Round 3
// baseline (6712.658 us; speedup 1.0000x reference)
//
#include <hip/hip_runtime.h>
#include <hip/hip_bf16.h>
#include <math.h>

// ---------------- problem constants ----------------
#define BD 8
#define TT 512
#define DD 1024
#define HH 16
#define LL 2
#define EE 8
#define KKTOP 2
#define DFF 4096
#define NTOK (BD*TT)           // 4096
#define CAP  (NTOK*KKTOP/EE)   // 1024
#define HD   64

typedef __attribute__((ext_vector_type(8))) short short8;
typedef __attribute__((ext_vector_type(4))) float f32x4;

#define MFMA_BF16(a,b,c) __builtin_amdgcn_mfma_f32_16x16x32_bf16((a),(b),(c),0,0,0)

#define GLOAD16(g, l) __builtin_amdgcn_global_load_lds( \
    (const __attribute__((address_space(1))) void*)(g), \
    (__attribute__((address_space(3))) void*)(l), 16, 0, 0)

// ---------------- helpers ----------------
__device__ __forceinline__ float wred(float v) {
#pragma unroll
  for (int off = 32; off; off >>= 1) v += __shfl_xor(v, off, 64);
  return v;
}

__device__ __forceinline__ ushort f2bf(float v) {
  uint x = __float_as_uint(v);
  uint r = (x + 0x7FFFu + ((x >> 16) & 1u)) >> 16;   // RN-even; inputs never NaN/Inf
  return (ushort)r;
}
__device__ __forceinline__ float bf2f(ushort u) {
  return __uint_as_float(((uint)u) << 16);
}
__device__ __forceinline__ void split3(float v, ushort& a, ushort& b, ushort& c) {
  a = f2bf(v); float r = v - bf2f(a);
  b = f2bf(r); r -= bf2f(b);
  c = f2bf(r);
}
__device__ __forceinline__ void store16(ushort* dst, const ushort* s) {
  uint pk[8];
#pragma unroll
  for (int j = 0; j < 8; ++j) pk[j] = (uint)s[2*j] | ((uint)s[2*j+1] << 16);
  ((uint4*)dst)[0] = *(const uint4*)&pk[0];
  ((uint4*)dst)[1] = *(const uint4*)&pk[4];
}

// ---------------- embedding ----------------
__global__ __launch_bounds__(256) void embed_kernel(
    const int* __restrict__ ids, const float* __restrict__ tok,
    const float* __restrict__ pos, float* __restrict__ x)
{
  int n  = blockIdx.x;
  int d4 = threadIdx.x;
  int t  = n % TT;
  int id = ids[n];
  float4 a = ((const float4*)(tok + (size_t)id * DD))[d4];
  float4 p = ((const float4*)(pos + (size_t)t  * DD))[d4];
  float4 r;
  r.x = a.x + p.x; r.y = a.y + p.y; r.z = a.z + p.z; r.w = a.w + p.w;
  ((float4*)(x + (size_t)n * DD))[d4] = r;
}

// ---------------- layernorm ----------------
__global__ __launch_bounds__(256) void ln_kernel(
    const float* __restrict__ in, const float* __restrict__ g,
    const float* __restrict__ b, float* __restrict__ out)
{
  int n = blockIdx.x, tid = threadIdx.x;
  float4 v = ((const float4*)(in + (size_t)n * DD))[tid];
  float s  = v.x + v.y + v.z + v.w;
  float ss = v.x*v.x + v.y*v.y + v.z*v.z + v.w*v.w;
  s = wred(s); ss = wred(ss);
  __shared__ float rs[4], rss[4];
  int wid = tid >> 6, lane = tid & 63;
  if (lane == 0) { rs[wid] = s; rss[wid] = ss; }
  __syncthreads();
  float S  = rs[0] + rs[1] + rs[2] + rs[3];
  float SS = rss[0] + rss[1] + rss[2] + rss[3];
  float mean = S * (1.f / DD);
  float var  = SS * (1.f / DD) - mean * mean;
  float rstd = rsqrtf(var + 1e-5f);
  float4 gv = ((const float4*)g)[tid];
  float4 bv = ((const float4*)b)[tid];
  float4 o;
  o.x = (v.x - mean) * rstd * gv.x + bv.x;
  o.y = (v.y - mean) * rstd * gv.y + bv.y;
  o.z = (v.z - mean) * rstd * gv.z + bv.z;
  o.w = (v.w - mean) * rstd * gv.w + bv.w;
  ((float4*)(out + (size_t)n * DD))[tid] = o;
}

// ---------------- weight conversion: W[K][N] fp32 -> tiled bf16 x3 planes ----------------
// Tile layout per plane p, expert e: idx = (((e*3+p)*NT + nt)*KT + kt)*4096 + n_loc*32 + k_loc
__global__ __launch_bounds__(256) void convert_w(
    const float* __restrict__ W, ushort* __restrict__ Wt,
    int N, int NT, int KT, long strideE)
{
  __shared__ float tile[32][128];
  int nt = blockIdx.x, kt = blockIdx.y, e = blockIdx.z;
  int t = threadIdx.x;
  const float* src = W + (size_t)e * strideE + (size_t)(kt * 32) * N + nt * 128;
  int kk = t >> 3, f0 = t & 7;
#pragma unroll
  for (int i = 0; i < 4; ++i) {
    float4 v = *(const float4*)(src + (size_t)kk * N + 4 * (f0 + 8 * i));
    ((float4*)&tile[kk][0])[f0 + 8 * i] = v;
  }
  __syncthreads();
  int n = t >> 1, half = t & 1, k16 = half * 16;
  ushort ha[16], ma[16], la[16];
#pragma unroll
  for (int j = 0; j < 16; ++j) split3(tile[k16 + j][n], ha[j], ma[j], la[j]);
  size_t pstride = (size_t)NT * KT * 4096;
  size_t base = (((size_t)(e * 3) * NT + nt) * KT + kt) * 4096 + n * 32 + k16;
  store16(Wt + base,               ha);
  store16(Wt + base + pstride,     ma);
  store16(Wt + base + 2 * pstride, la);
}

// ---------------- activation conversion: A[rows][Kc] fp32 (optional gather) -> tiled x3 ----------------
__global__ __launch_bounds__(256) void convert_a(
    const float* __restrict__ A, ushort* __restrict__ At,
    int Kc, int MT, int KT, const int* __restrict__ sel, int useSel)
{
  int mt = blockIdx.x, kt = blockIdx.y, e = blockIdx.z;
  int t = threadIdx.x;
  int mloc = t >> 1, half = t & 1;
  int m = mt * 128 + mloc;
  int row = useSel ? sel[e * CAP + m] : m;
  float vv[16];
  if (row < NTOK) {
    const float* src = A + (size_t)row * Kc + kt * 32 + half * 16;
#pragma unroll
    for (int i = 0; i < 4; ++i) {
      float4 v = *(const float4*)(src + 4 * i);
      vv[4*i+0] = v.x; vv[4*i+1] = v.y; vv[4*i+2] = v.z; vv[4*i+3] = v.w;
    }
  } else {
#pragma unroll
    for (int i = 0; i < 16; ++i) vv[i] = 0.f;
  }
  ushort ha[16], ma[16], la[16];
#pragma unroll
  for (int j = 0; j < 16; ++j) split3(vv[j], ha[j], ma[j], la[j]);
  size_t pstride = (size_t)MT * KT * 4096;
  size_t base = (((size_t)(e * 3) * MT + mt) * KT + kt) * 4096 + mloc * 32 + half * 16;
  store16(At + base,               ha);
  store16(At + base + pstride,     ma);
  store16(At + base + 2 * pstride, la);
}

// ---------------- bf16x3 MFMA GEMM, 128x128 tile, BK=32 ----------------
// MODE 0: C = A@B        MODE 1: C += A@B
// MODE 2: Ht = split3(relu(A@B + bias))   (tiled output, becomes next A)
// MODE 3: atomicAdd(Xout[sel[m]][col], (A@B + bias[col]) * geb[m])
template<int MODE>
__global__ __launch_bounds__(256, 2) void gemm3(
    const ushort* __restrict__ At, const ushort* __restrict__ Bt,
    float* __restrict__ C, int Ncol, int KT, int MTa, int NTb,
    const float* __restrict__ bias, long biasStride,
    const int* __restrict__ sel, const float* __restrict__ geb,
    float* __restrict__ Xout, ushort* __restrict__ Ht)
{
  __shared__ __align__(16) ushort sA[3][4096];
  __shared__ __align__(16) ushort sB[3][4096];
  __shared__ int   selL[128];
  __shared__ float gebL[128];

  const int tid = threadIdx.x, lane = tid & 63, wid = tid >> 6;
  const int wy = wid >> 1, wx = wid & 1;
  const int nb = blockIdx.x, mb = blockIdx.y, e = blockIdx.z;

  if (MODE == 3 && tid < 128) {
    selL[tid] = sel[e * CAP + mb * 128 + tid];
    gebL[tid] = geb[e * CAP + mb * 128 + tid];
  }

  const ushort* Ab[3]; const ushort* Bb[3];
#pragma unroll
  for (int p = 0; p < 3; ++p) {
    Ab[p] = At + ((size_t)((e * 3 + p) * MTa + mb)) * KT * 4096;
    Bb[p] = Bt + ((size_t)((e * 3 + p) * NTb + nb)) * KT * 4096;
  }

  f32x4 acc[4][4];
#pragma unroll
  for (int i = 0; i < 4; ++i)
#pragma unroll
    for (int j = 0; j < 4; ++j) acc[i][j] = (f32x4){0.f, 0.f, 0.f, 0.f};

  for (int kt = 0; kt < KT; ++kt) {
#pragma unroll
    for (int p = 0; p < 3; ++p) {
#pragma unroll
      for (int j = 0; j < 2; ++j) {
        int boff = wid * 2048 + j * 1024;
        GLOAD16((const char*)(Ab[p] + (size_t)kt * 4096) + boff + lane * 16,
                (char*)&sA[p][0] + boff);
        GLOAD16((const char*)(Bb[p] + (size_t)kt * 4096) + boff + lane * 16,
                (char*)&sB[p][0] + boff);
      }
    }
    __syncthreads();

    short8 af[4][3], bfr[4][3];
    const int k8 = (lane >> 4) * 8;
#pragma unroll
    for (int i = 0; i < 4; ++i) {
      int ra = (wy * 64 + i * 16 + (lane & 15)) * 32 + k8;
      int rb = (wx * 64 + i * 16 + (lane & 15)) * 32 + k8;
#pragma unroll
      for (int p = 0; p < 3; ++p) {
        af[i][p]  = *(const short8*)&sA[p][ra];
        bfr[i][p] = *(const short8*)&sB[p][rb];
      }
    }
#pragma unroll
    for (int i = 0; i < 4; ++i)
#pragma unroll
      for (int j = 0; j < 4; ++j) {
        f32x4 c = acc[i][j];
        c = MFMA_BF16(af[i][0], bfr[j][0], c);  // hi*hi
        c = MFMA_BF16(af[i][0], bfr[j][1], c);  // hi*mid
        c = MFMA_BF16(af[i][1], bfr[j][0], c);  // mid*hi
        c = MFMA_BF16(af[i][0], bfr[j][2], c);  // hi*lo
        c = MFMA_BF16(af[i][2], bfr[j][0], c);  // lo*hi
        c = MFMA_BF16(af[i][1], bfr[j][1], c);  // mid*mid
        acc[i][j] = c;
      }
    __syncthreads();
  }

  // epilogue
#pragma unroll
  for (int i = 0; i < 4; ++i) {
#pragma unroll
    for (int j = 0; j < 4; ++j) {
      int col  = nb * 128 + wx * 64 + j * 16 + (lane & 15);
      float bcol = 0.f;
      if (MODE == 2 || MODE == 3) bcol = bias[(size_t)e * biasStride + col];
#pragma unroll
      for (int r = 0; r < 4; ++r) {
        int rloc = wy * 64 + i * 16 + 4 * (lane >> 4) + r;
        int row  = mb * 128 + rloc;
        float v = acc[i][j][r];
        if (MODE == 0) {
          C[(size_t)row * Ncol + col] = v;
        } else if (MODE == 1) {
          C[(size_t)row * Ncol + col] += v;
        } else if (MODE == 2) {
          float hv = fmaxf(v + bcol, 0.f);
          ushort a, b2, c2; split3(hv, a, b2, c2);
          size_t pstride = (size_t)8 * 128 * 4096;   // MT_h=8, KT_h=128
          size_t base = (((size_t)(e * 3) * 8 + mb) * 128 + (col >> 5)) * 4096
                        + (size_t)rloc * 32 + (col & 31);
          Ht[base] = a; Ht[base + pstride] = b2; Ht[base + 2 * pstride] = c2;
        } else {
          int tok = selL[rloc];
          if (tok < NTOK)
            atomicAdd(&Xout[(size_t)tok * DD + col], (v + bcol) * gebL[rloc]);
        }
      }
    }
  }
}

// ---------------- fp32 tiled GEMM (fallback path) ----------------
#define BM 64
#define BN 64
#define BK 16

template<int MODE>
__global__ __launch_bounds__(256) void gemm_f32(
    const float* __restrict__ A, const float* __restrict__ Bm,
    float* __restrict__ C, int M, int Ncol, int Kc,
    const float* __restrict__ bias,
    const int* __restrict__ sel, const float* __restrict__ geb,
    float* __restrict__ Xout,
    long sAe, long sBe, long sCe, long sBiasE)
{
  __shared__ float As[BK][BM + 4];
  __shared__ float Bs[BK][BN + 4];
  __shared__ int rowidx[BM];

  const int e  = blockIdx.z;
  const int tid = threadIdx.x;
  const int m0 = blockIdx.y * BM, n0 = blockIdx.x * BN;

  const float* Ap = A  + (size_t)e * sAe;
  const float* Bp = Bm + (size_t)e * sBe;

  if (MODE == 2 || MODE == 3) {
    if (tid < BM) rowidx[tid] = sel[e * CAP + m0 + tid];
    __syncthreads();
  }

  const int ar = tid >> 2, ac = (tid & 3) * 4;
  const int br = tid >> 4, bc = (tid & 15) * 4;
  const int tx = tid & 15, ty = tid >> 4;

  float acc[4][4] = {{0.f}};

  for (int k0 = 0; k0 < Kc; k0 += BK) {
    float4 av;
    if (MODE == 2) {
      int row = rowidx[ar];
      if (row < NTOK) av = *(const float4*)(Ap + (size_t)row * Kc + k0 + ac);
      else            av = make_float4(0.f, 0.f, 0.f, 0.f);
    } else {
      av = *(const float4*)(Ap + (size_t)(m0 + ar) * Kc + k0 + ac);
    }
    As[ac + 0][ar] = av.x; As[ac + 1][ar] = av.y;
    As[ac + 2][ar] = av.z; As[ac + 3][ar] = av.w;
    float4 bv = *(const float4*)(Bp + (size_t)(k0 + br) * Ncol + n0 + bc);
    *(float4*)&Bs[br][bc] = bv;
    __syncthreads();
#pragma unroll
    for (int kk = 0; kk < BK; ++kk) {
      float a[4];
#pragma unroll
      for (int i = 0; i < 4; ++i) a[i] = As[kk][ty * 4 + i];
      float4 b4 = *(const float4*)&Bs[kk][tx * 4];
      float bq[4] = {b4.x, b4.y, b4.z, b4.w};
#pragma unroll
      for (int i = 0; i < 4; ++i)
#pragma unroll
        for (int j = 0; j < 4; ++j)
          acc[i][j] = fmaf(a[i], bq[j], acc[i][j]);
    }
    __syncthreads();
  }

  if (MODE == 0) {
#pragma unroll
    for (int i = 0; i < 4; ++i) {
      float4 o = make_float4(acc[i][0], acc[i][1], acc[i][2], acc[i][3]);
      *(float4*)(C + (size_t)(m0 + ty * 4 + i) * Ncol + n0 + tx * 4) = o;
    }
  } else if (MODE == 1) {
#pragma unroll
    for (int i = 0; i < 4; ++i) {
      float* cp = C + (size_t)(m0 + ty * 4 + i) * Ncol + n0 + tx * 4;
      float4 o = *(const float4*)cp;
      o.x += acc[i][0]; o.y += acc[i][1]; o.z += acc[i][2]; o.w += acc[i][3];
      *(float4*)cp = o;
    }
  } else if (MODE == 2) {
    float4 bb = *(const float4*)(bias + (size_t)e * sBiasE + n0 + tx * 4);
    float bq[4] = {bb.x, bb.y, bb.z, bb.w};
#pragma unroll
    for (int i = 0; i < 4; ++i) {
      float4 o;
      o.x = fmaxf(acc[i][0] + bq[0], 0.f);
      o.y = fmaxf(acc[i][1] + bq[1], 0.f);
      o.z = fmaxf(acc[i][2] + bq[2], 0.f);
      o.w = fmaxf(acc[i][3] + bq[3], 0.f);
      *(float4*)(C + (size_t)e * sCe + (size_t)(m0 + ty * 4 + i) * Ncol + n0 + tx * 4) = o;
    }
  } else {
    float4 bb = *(const float4*)(bias + (size_t)e * sBiasE + n0 + tx * 4);
    float bq[4] = {bb.x, bb.y, bb.z, bb.w};
#pragma unroll
    for (int i = 0; i < 4; ++i) {
      int row = rowidx[ty * 4 + i];
      if (row < NTOK) {
        float gv = geb[e * CAP + m0 + ty * 4 + i];
        float* dst = Xout + (size_t)row * DD + n0 + tx * 4;
        atomicAdd(dst + 0, (acc[i][0] + bq[0]) * gv);
        atomicAdd(dst + 1, (acc[i][1] + bq[1]) * gv);
        atomicAdd(dst + 2, (acc[i][2] + bq[2]) * gv);
        atomicAdd(dst + 3, (acc[i][3] + bq[3]) * gv);
      }
    }
  }
}

// ---------------- attention ----------------
__global__ __launch_bounds__(256) void attn_kernel(
    const float* __restrict__ qkv, float* __restrict__ o)
{
  int wid = threadIdx.x >> 6, lane = threadIdx.x & 63;
  int q = blockIdx.x * 4 + wid;
  int h = blockIdx.y, b = blockIdx.z;
  const size_t rs = 3 * DD;
  float qv = qkv[(size_t)(b * TT + q) * rs + h * HD + lane];
  const float* kbase = qkv + (size_t)(b * TT) * rs + DD + h * HD + lane;
  const float* vbase = kbase + DD;
  float m = -INFINITY, lsum = 0.f, oacc = 0.f;
  for (int k = 0; k < TT; ++k) {
    float kv = kbase[(size_t)k * rs];
    float vv = vbase[(size_t)k * rs];
    float s = wred(qv * kv) * 0.125f;
    float mn = fmaxf(m, s);
    float corr = __expf(m - mn);
    float p = __expf(s - mn);
    lsum = lsum * corr + p;
    oacc = oacc * corr + p * vv;
    m = mn;
  }
  o[(size_t)(b * TT + q) * DD + h * HD + lane] = oacc / lsum;
}

// ---------------- router ----------------
__global__ __launch_bounds__(256) void router_kernel(
    const float* __restrict__ xln,
    const float* __restrict__ rt_w, const float* __restrict__ rt_b,
    const float* __restrict__ nz_w, const float* __restrict__ nz_b,
    float* __restrict__ rtbuf)
{
  int n = blockIdx.x, tid = threadIdx.x;
  float4 xv = ((const float4*)(xln + (size_t)n * DD))[tid];
  float xs[4] = {xv.x, xv.y, xv.z, xv.w};
  float ar[EE] = {0.f}, an[EE] = {0.f};
  const float* rw = rt_w + (size_t)tid * 4 * EE;
  const float* nw = nz_w + (size_t)tid * 4 * EE;
#pragma unroll
  for (int j = 0; j < 4; ++j)
#pragma unroll
    for (int e2 = 0; e2 < EE; ++e2) {
      ar[e2] = fmaf(xs[j], rw[j * EE + e2], ar[e2]);
      an[e2] = fmaf(xs[j], nw[j * EE + e2], an[e2]);
    }
#pragma unroll
  for (int e2 = 0; e2 < EE; ++e2) { ar[e2] = wred(ar[e2]); an[e2] = wred(an[e2]); }
  __shared__ float sm[4][16];
  int wid = tid >> 6, lane = tid & 63;
  if (lane == 0) {
#pragma unroll
    for (int e2 = 0; e2 < EE; ++e2) { sm[wid][e2] = ar[e2]; sm[wid][8 + e2] = an[e2]; }
  }
  __syncthreads();
  if (tid < 16) {
    float v = sm[0][tid] + sm[1][tid] + sm[2][tid] + sm[3][tid];
    v += (tid < 8) ? rt_b[tid] : nz_b[tid - 8];
    rtbuf[n * 16 + tid] = v;
  }
}

// ---------------- noisy top-2 ----------------
__global__ __launch_bounds__(256) void topk_kernel(
    const float* __restrict__ rtbuf, const float* __restrict__ noise,
    float* __restrict__ gates, int* __restrict__ maskb)
{
  int n = blockIdx.x * 256 + threadIdx.x;
  float nv[EE];
#pragma unroll
  for (int e = 0; e < EE; ++e) {
    float lg = rtbuf[n * 16 + e];
    float pz = rtbuf[n * 16 + 8 + e];
    float sp = fmaxf(pz, 0.f) + log1pf(expf(-fabsf(pz)));
    nv[e] = lg + noise[(size_t)n * EE + e] * sp;
  }
  int i0 = 0; float v0 = nv[0];
#pragma unroll
  for (int e = 1; e < EE; ++e) if (nv[e] > v0) { v0 = nv[e]; i0 = e; }
  int i1 = -1; float v1 = -INFINITY;
#pragma unroll
  for (int e = 0; e < EE; ++e) if (e != i0 && nv[e] > v1) { v1 = nv[e]; i1 = e; }
  float e1 = expf(v1 - v0);
  float g0 = 1.f / (1.f + e1);
  float g1 = e1 / (1.f + e1);
#pragma unroll
  for (int e = 0; e < EE; ++e) gates[(size_t)n * EE + e] = 0.f;
  gates[(size_t)n * EE + i0] = g0;
  gates[(size_t)n * EE + i1] = g1;
  maskb[n] = (1 << i0) | (1 << i1);
}

// ---------------- per-expert capacity scan ----------------
__global__ __launch_bounds__(256) void capacity_kernel(
    const int* __restrict__ maskb, const float* __restrict__ gates,
    int* __restrict__ sel, float* __restrict__ geb)
{
  int e = blockIdx.x, tid = threadIdx.x;
  __shared__ int s[256];
  __shared__ int soff;
  for (int i = tid; i < CAP; i += 256) { sel[e * CAP + i] = NTOK; geb[e * CAP + i] = 0.f; }
  if (tid == 0) soff = 0;
  __syncthreads();
  for (int c = 0; c < NTOK; c += 256) {
    int n = c + tid;
    int m = (maskb[n] >> e) & 1;
    s[tid] = m;
    __syncthreads();
    for (int off = 1; off < 256; off <<= 1) {
      int v = (tid >= off) ? s[tid - off] : 0;
      __syncthreads();
      s[tid] += v;
      __syncthreads();
    }
    int incl = s[tid], tot = s[255];
    int rank = soff + incl - 1;
    if (m && rank < CAP) {
      sel[e * CAP + rank] = n;
      geb[e * CAP + rank] = gates[(size_t)n * EE + e];
    }
    __syncthreads();
    if (tid == 0) soff += tot;
    __syncthreads();
  }
}

// ---------------- launch ----------------
extern "C" void kernel_launch(void* const* d_in, const int* in_sizes, int n_in,
                              void* d_out, int out_size, void* d_ws, size_t ws_size,
                              hipStream_t stream)
{
  (void)in_sizes; (void)n_in; (void)out_size;
  const int*   ids   = (const int*)  d_in[0];
  const float* noise = (const float*)d_in[1];
  const float* tok   = (const float*)d_in[2];
  const float* pos   = (const float*)d_in[3];
  const float* ln1g  = (const float*)d_in[4];
  const float* ln1b  = (const float*)d_in[5];
  const float* ln2g  = (const float*)d_in[6];
  const float* ln2b  = (const float*)d_in[7];
  const float* qkvw  = (const float*)d_in[8];
  const float* outw  = (const float*)d_in[9];
  const float* rtw   = (const float*)d_in[10];
  const float* rtb   = (const float*)d_in[11];
  const float* nzw   = (const float*)d_in[12];
  const float* nzb   = (const float*)d_in[13];
  const float* ew1   = (const float*)d_in[14];
  const float* eb1   = (const float*)d_in[15];
  const float* ew2   = (const float*)d_in[16];
  const float* eb2   = (const float*)d_in[17];
  const float* lnfg  = (const float*)d_in[18];
  const float* lnfb  = (const float*)d_in[19];
  float* outp = (float*)d_out;

  // ---- fast-path workspace layout (~554 MB) ----
  size_t off = 0;
  auto alloc = [&](size_t bytes) {
    char* p = (char*)d_ws + off;
    off = (off + bytes + 255) & ~(size_t)255;
    return p;
  };
  float*  x      = (float*) alloc((size_t)NTOK * DD * 4);
  float*  xln    = (float*) alloc((size_t)NTOK * DD * 4);
  float*  obuf   = (float*) alloc((size_t)NTOK * DD * 4);
  float*  qkvbuf = (float*) alloc((size_t)NTOK * 3 * DD * 4);
  ushort* AT     = (ushort*)alloc((size_t)EE * 3 * 8 * 32 * 4096 * 2);      // 50.3 MB
  ushort* WT     = (ushort*)alloc((size_t)EE * 3 * 32 * 32 * 4096 * 2);     // 201 MB
  ushort* hT     = (ushort*)alloc((size_t)EE * 3 * 8 * 128 * 4096 * 2);     // 201 MB
  float*  rtbuf  = (float*) alloc((size_t)NTOK * 16 * 4);
  float*  gates  = (float*) alloc((size_t)NTOK * EE * 4);
  float*  geb    = (float*) alloc((size_t)EE * CAP * 4);
  int*    sel    = (int*)   alloc((size_t)EE * CAP * 4);
  int*    maskb  = (int*)   alloc((size_t)NTOK * 4);
  bool fast = (off <= ws_size);

  if (fast) {
    embed_kernel<<<NTOK, 256, 0, stream>>>(ids, tok, pos, x);

    for (int l = 0; l < LL; ++l) {
      ln_kernel<<<NTOK, 256, 0, stream>>>(x, ln1g + l * DD, ln1b + l * DD, xln);

      // QKV = xln @ qkv_w[l]
      convert_a<<<dim3(32, 32, 1), 256, 0, stream>>>(xln, AT, DD, 32, 32, nullptr, 0);
      convert_w<<<dim3(24, 32, 1), 256, 0, stream>>>(qkvw + (size_t)l * DD * 3 * DD, WT,
                                                     3 * DD, 24, 32, 0);
      gemm3<0><<<dim3(24, 32, 1), 256, 0, stream>>>(AT, WT, qkvbuf, 3 * DD, 32, 32, 24,
                                                    nullptr, 0, nullptr, nullptr, nullptr, nullptr);

      attn_kernel<<<dim3(TT / 4, HH, BD), 256, 0, stream>>>(qkvbuf, obuf);

      // x += obuf @ out_w[l]
      convert_a<<<dim3(32, 32, 1), 256, 0, stream>>>(obuf, AT, DD, 32, 32, nullptr, 0);
      convert_w<<<dim3(8, 32, 1), 256, 0, stream>>>(outw + (size_t)l * DD * DD, WT,
                                                    DD, 8, 32, 0);
      gemm3<1><<<dim3(8, 32, 1), 256, 0, stream>>>(AT, WT, x, DD, 32, 32, 8,
                                                   nullptr, 0, nullptr, nullptr, nullptr, nullptr);

      ln_kernel<<<NTOK, 256, 0, stream>>>(x, ln2g + l * DD, ln2b + l * DD, xln);

      router_kernel<<<NTOK, 256, 0, stream>>>(
          xln, rtw + (size_t)l * DD * EE, rtb + l * EE,
          nzw + (size_t)l * DD * EE, nzb + l * EE, rtbuf);
      topk_kernel<<<NTOK / 256, 256, 0, stream>>>(
          rtbuf, noise + (size_t)l * NTOK * EE, gates, maskb);
      capacity_kernel<<<EE, 256, 0, stream>>>(maskb, gates, sel, geb);

      // h = relu(xe @ w1 + b1), tiled bf16x3 output
      convert_a<<<dim3(8, 32, EE), 256, 0, stream>>>(xln, AT, DD, 8, 32, sel, 1);
      convert_w<<<dim3(32, 32, EE), 256, 0, stream>>>(ew1 + (size_t)l * EE * DD * DFF, WT,
                                                      DFF, 32, 32, (long)DD * DFF);
      gemm3<2><<<dim3(32, 8, EE), 256, 0, stream>>>(AT, WT, nullptr, DFF, 32, 8, 32,
                                                    eb1 + (size_t)l * EE * DFF, DFF,
                                                    nullptr, nullptr, nullptr, hT);

      // x[sel] += (h @ w2 + b2) * gate
      convert_w<<<dim3(8, 128, EE), 256, 0, stream>>>(ew2 + (size_t)l * EE * DFF * DD, WT,
                                                      DD, 8, 128, (long)DFF * DD);
      gemm3<3><<<dim3(8, 8, EE), 256, 0, stream>>>(hT, WT, nullptr, DD, 128, 8, 8,
                                                   eb2 + (size_t)l * EE * DD, DD,
                                                   sel, geb, x, nullptr);
    }

    ln_kernel<<<NTOK, 256, 0, stream>>>(x, lnfg, lnfb, outp);
    return;
  }

  // ---- fp32 fallback path (~237 MB) ----
  {
    float* ws     = (float*)d_ws;
    float* fx     = ws;
    float* fxln   = fx     + (size_t)NTOK * DD;
    float* fqkv   = fxln   + (size_t)NTOK * DD;
    float* fobuf  = fqkv   + (size_t)NTOK * 3 * DD;
    float* fh     = fobuf  + (size_t)NTOK * DD;
    float* frt    = fh     + (size_t)EE * CAP * DFF;
    float* fgates = frt    + (size_t)NTOK * 16;
    float* fgeb   = fgates + (size_t)NTOK * EE;
    int*   fsel   = (int*)(fgeb + (size_t)EE * CAP);
    int*   fmask  = fsel + (size_t)EE * CAP;

    embed_kernel<<<NTOK, 256, 0, stream>>>(ids, tok, pos, fx);

    for (int l = 0; l < LL; ++l) {
      ln_kernel<<<NTOK, 256, 0, stream>>>(fx, ln1g + l * DD, ln1b + l * DD, fxln);
      gemm_f32<0><<<dim3(3 * DD / BN, NTOK / BM, 1), 256, 0, stream>>>(
          fxln, qkvw + (size_t)l * DD * 3 * DD, fqkv, NTOK, 3 * DD, DD,
          nullptr, nullptr, nullptr, nullptr, 0, 0, 0, 0);
      attn_kernel<<<dim3(TT / 4, HH, BD), 256, 0, stream>>>(fqkv, fobuf);
      gemm_f32<1><<<dim3(DD / BN, NTOK / BM, 1), 256, 0, stream>>>(
          fobuf, outw + (size_t)l * DD * DD, fx, NTOK, DD, DD,
          nullptr, nullptr, nullptr, nullptr, 0, 0, 0, 0);
      ln_kernel<<<NTOK, 256, 0, stream>>>(fx, ln2g + l * DD, ln2b + l * DD, fxln);
      router_kernel<<<NTOK, 256, 0, stream>>>(
          fxln, rtw + (size_t)l * DD * EE, rtb + l * EE,
          nzw + (size_t)l * DD * EE, nzb + l * EE, frt);
      topk_kernel<<<NTOK / 256, 256, 0, stream>>>(
          frt, noise + (size_t)l * NTOK * EE, fgates, fmask);
      capacity_kernel<<<EE, 256, 0, stream>>>(fmask, fgates, fsel, fgeb);
      gemm_f32<2><<<dim3(DFF / BN, CAP / BM, EE), 256, 0, stream>>>(
          fxln, ew1 + (size_t)l * EE * DD * DFF, fh, CAP, DFF, DD,
          eb1 + (size_t)l * EE * DFF, fsel, nullptr, nullptr,
          0, (long)DD * DFF, (long)CAP * DFF, DFF);
      gemm_f32<3><<<dim3(DD / BN, CAP / BM, EE), 256, 0, stream>>>(
          fh, ew2 + (size_t)l * EE * DFF * DD, nullptr, CAP, DD, DFF,
          eb2 + (size_t)l * EE * DD, fsel, fgeb, fx,
          (long)CAP * DFF, (long)DFF * DD, 0, DD);
    }

    ln_kernel<<<NTOK, 256, 0, stream>>>(fx, lnfg, lnfb, outp);
  }
}

// Round 4
// 3177.917 us; speedup vs baseline: 2.1123x; 2.1123x over previous
//
#include <hip/hip_runtime.h>
#include <hip/hip_bf16.h>
#include <math.h>

// ---------------- problem constants ----------------
#define BD 8
#define TT 512
#define DD 1024
#define HH 16
#define LL 2
#define EE 8
#define KKTOP 2
#define DFF 4096
#define NTOK (BD*TT)           // 4096
#define CAP  (NTOK*KKTOP/EE)   // 1024
#define HD   64

typedef __attribute__((ext_vector_type(8))) short short8;
typedef __attribute__((ext_vector_type(4))) float f32x4;

#define MFMA_BF16(a,b,c) __builtin_amdgcn_mfma_f32_16x16x32_bf16((a),(b),(c),0,0,0)

#define GLOAD16(g, l) __builtin_amdgcn_global_load_lds( \
    (const __attribute__((address_space(1))) void*)(g), \
    (__attribute__((address_space(3))) void*)(l), 16, 0, 0)

// ---------------- helpers ----------------
__device__ __forceinline__ float wred(float v) {
#pragma unroll
  for (int off = 32; off; off >>= 1) v += __shfl_xor(v, off, 64);
  return v;
}

__device__ __forceinline__ ushort f2bf(float v) {
  uint x = __float_as_uint(v);
  uint r = (x + 0x7FFFu + ((x >> 16) & 1u)) >> 16;   // RN-even; inputs never NaN/Inf
  return (ushort)r;
}
__device__ __forceinline__ float bf2f(ushort u) {
  return __uint_as_float(((uint)u) << 16);
}
__device__ __forceinline__ void split3(float v, ushort& a, ushort& b, ushort& c) {
  a = f2bf(v); float r = v - bf2f(a);
  b = f2bf(r); r -= bf2f(b);
  c = f2bf(r);
}
__device__ __forceinline__ void store16(ushort* dst, const ushort* s) {
  uint pk[8];
#pragma unroll
  for (int j = 0; j < 8; ++j) pk[j] = (uint)s[2*j] | ((uint)s[2*j+1] << 16);
  ((uint4*)dst)[0] = *(const uint4*)&pk[0];
  ((uint4*)dst)[1] = *(const uint4*)&pk[4];
}

// ---------------- embedding ----------------
__global__ __launch_bounds__(256) void embed_kernel(
    const int* __restrict__ ids, const float* __restrict__ tok,
    const float* __restrict__ pos, float* __restrict__ x)
{
  int n  = blockIdx.x;
  int d4 = threadIdx.x;
  int t  = n % TT;
  int id = ids[n];
  float4 a = ((const float4*)(tok + (size_t)id * DD))[d4];
  float4 p = ((const float4*)(pos + (size_t)t  * DD))[d4];
  float4 r;
  r.x = a.x + p.x; r.y = a.y + p.y; r.z = a.z + p.z; r.w = a.w + p.w;
  ((float4*)(x + (size_t)n * DD))[d4] = r;
}

// ---------------- layernorm ----------------
__global__ __launch_bounds__(256) void ln_kernel(
    const float* __restrict__ in, const float* __restrict__ g,
    const float* __restrict__ b, float* __restrict__ out)
{
  int n = blockIdx.x, tid = threadIdx.x;
  float4 v = ((const float4*)(in + (size_t)n * DD))[tid];
  float s  = v.x + v.y + v.z + v.w;
  float ss = v.x*v.x + v.y*v.y + v.z*v.z + v.w*v.w;
  s = wred(s); ss = wred(ss);
  __shared__ float rs[4], rss[4];
  int wid = tid >> 6, lane = tid & 63;
  if (lane == 0) { rs[wid] = s; rss[wid] = ss; }
  __syncthreads();
  float S  = rs[0] + rs[1] + rs[2] + rs[3];
  float SS = rss[0] + rss[1] + rss[2] + rss[3];
  float mean = S * (1.f / DD);
  float var  = SS * (1.f / DD) - mean * mean;
  float rstd = rsqrtf(var + 1e-5f);
  float4 gv = ((const float4*)g)[tid];
  float4 bv = ((const float4*)b)[tid];
  float4 o;
  o.x = (v.x - mean) * rstd * gv.x + bv.x;
  o.y = (v.y - mean) * rstd * gv.y + bv.y;
  o.z = (v.z - mean) * rstd * gv.z + bv.z;
  o.w = (v.w - mean) * rstd * gv.w + bv.w;
  ((float4*)(out + (size_t)n * DD))[tid] = o;
}

// ---------------- weight conversion: W[K][N] fp32 -> tiled bf16 x3 planes ----------------
__global__ __launch_bounds__(256) void convert_w(
    const float* __restrict__ W, ushort* __restrict__ Wt,
    int N, int NT, int KT, long strideE)
{
  __shared__ float tile[32][128];
  int nt = blockIdx.x, kt = blockIdx.y, e = blockIdx.z;
  int t = threadIdx.x;
  const float* src = W + (size_t)e * strideE + (size_t)(kt * 32) * N + nt * 128;
  int kk = t >> 3, f0 = t & 7;
#pragma unroll
  for (int i = 0; i < 4; ++i) {
    float4 v = *(const float4*)(src + (size_t)kk * N + 4 * (f0 + 8 * i));
    ((float4*)&tile[kk][0])[f0 + 8 * i] = v;
  }
  __syncthreads();
  int n = t >> 1, half = t & 1, k16 = half * 16;
  ushort ha[16], ma[16], la[16];
#pragma unroll
  for (int j = 0; j < 16; ++j) split3(tile[k16 + j][n], ha[j], ma[j], la[j]);
  size_t pstride = (size_t)NT * KT * 4096;
  size_t base = (((size_t)(e * 3) * NT + nt) * KT + kt) * 4096 + n * 32 + k16;
  store16(Wt + base,               ha);
  store16(Wt + base + pstride,     ma);
  store16(Wt + base + 2 * pstride, la);
}

// ---------------- activation conversion ----------------
__global__ __launch_bounds__(256) void convert_a(
    const float* __restrict__ A, ushort* __restrict__ At,
    int Kc, int MT, int KT, const int* __restrict__ sel, int useSel)
{
  int mt = blockIdx.x, kt = blockIdx.y, e = blockIdx.z;
  int t = threadIdx.x;
  int mloc = t >> 1, half = t & 1;
  int m = mt * 128 + mloc;
  int row = useSel ? sel[e * CAP + m] : m;
  float vv[16];
  if (row < NTOK) {
    const float* src = A + (size_t)row * Kc + kt * 32 + half * 16;
#pragma unroll
    for (int i = 0; i < 4; ++i) {
      float4 v = *(const float4*)(src + 4 * i);
      vv[4*i+0] = v.x; vv[4*i+1] = v.y; vv[4*i+2] = v.z; vv[4*i+3] = v.w;
    }
  } else {
#pragma unroll
    for (int i = 0; i < 16; ++i) vv[i] = 0.f;
  }
  ushort ha[16], ma[16], la[16];
#pragma unroll
  for (int j = 0; j < 16; ++j) split3(vv[j], ha[j], ma[j], la[j]);
  size_t pstride = (size_t)MT * KT * 4096;
  size_t base = (((size_t)(e * 3) * MT + mt) * KT + kt) * 4096 + mloc * 32 + half * 16;
  store16(At + base,               ha);
  store16(At + base + pstride,     ma);
  store16(At + base + 2 * pstride, la);
}

// ---------------- bf16x3 MFMA GEMM, 128x128 tile, BK=32 ----------------
template<int MODE>
__global__ __launch_bounds__(256, 2) void gemm3(
    const ushort* __restrict__ At, const ushort* __restrict__ Bt,
    float* __restrict__ C, int Ncol, int KT, int MTa, int NTb,
    const float* __restrict__ bias, long biasStride,
    const int* __restrict__ sel, const float* __restrict__ geb,
    float* __restrict__ Xout, ushort* __restrict__ Ht)
{
  __shared__ __align__(16) ushort sA[3][4096];
  __shared__ __align__(16) ushort sB[3][4096];
  __shared__ int   selL[128];
  __shared__ float gebL[128];

  const int tid = threadIdx.x, lane = tid & 63, wid = tid >> 6;
  const int wy = wid >> 1, wx = wid & 1;
  const int nb = blockIdx.x, mb = blockIdx.y, e = blockIdx.z;

  if (MODE == 3 && tid < 128) {
    selL[tid] = sel[e * CAP + mb * 128 + tid];
    gebL[tid] = geb[e * CAP + mb * 128 + tid];
  }

  const ushort* Ab[3]; const ushort* Bb[3];
#pragma unroll
  for (int p = 0; p < 3; ++p) {
    Ab[p] = At + ((size_t)((e * 3 + p) * MTa + mb)) * KT * 4096;
    Bb[p] = Bt + ((size_t)((e * 3 + p) * NTb + nb)) * KT * 4096;
  }

  f32x4 acc[4][4];
#pragma unroll
  for (int i = 0; i < 4; ++i)
#pragma unroll
    for (int j = 0; j < 4; ++j) acc[i][j] = (f32x4){0.f, 0.f, 0.f, 0.f};

  for (int kt = 0; kt < KT; ++kt) {
#pragma unroll
    for (int p = 0; p < 3; ++p) {
#pragma unroll
      for (int j = 0; j < 2; ++j) {
        int boff = wid * 2048 + j * 1024;
        GLOAD16((const char*)(Ab[p] + (size_t)kt * 4096) + boff + lane * 16,
                (char*)&sA[p][0] + boff);
        GLOAD16((const char*)(Bb[p] + (size_t)kt * 4096) + boff + lane * 16,
                (char*)&sB[p][0] + boff);
      }
    }
    __syncthreads();

    short8 af[4][3], bfr[4][3];
    const int k8 = (lane >> 4) * 8;
#pragma unroll
    for (int i = 0; i < 4; ++i) {
      int ra = (wy * 64 + i * 16 + (lane & 15)) * 32 + k8;
      int rb = (wx * 64 + i * 16 + (lane & 15)) * 32 + k8;
#pragma unroll
      for (int p = 0; p < 3; ++p) {
        af[i][p]  = *(const short8*)&sA[p][ra];
        bfr[i][p] = *(const short8*)&sB[p][rb];
      }
    }
#pragma unroll
    for (int i = 0; i < 4; ++i)
#pragma unroll
      for (int j = 0; j < 4; ++j) {
        f32x4 c = acc[i][j];
        c = MFMA_BF16(af[i][0], bfr[j][0], c);
        c = MFMA_BF16(af[i][0], bfr[j][1], c);
        c = MFMA_BF16(af[i][1], bfr[j][0], c);
        c = MFMA_BF16(af[i][0], bfr[j][2], c);
        c = MFMA_BF16(af[i][2], bfr[j][0], c);
        c = MFMA_BF16(af[i][1], bfr[j][1], c);
        acc[i][j] = c;
      }
    __syncthreads();
  }

  // epilogue
#pragma unroll
  for (int i = 0; i < 4; ++i) {
#pragma unroll
    for (int j = 0; j < 4; ++j) {
      int col  = nb * 128 + wx * 64 + j * 16 + (lane & 15);
      float bcol = 0.f;
      if (MODE == 2 || MODE == 3) bcol = bias[(size_t)e * biasStride + col];
#pragma unroll
      for (int r = 0; r < 4; ++r) {
        int rloc = wy * 64 + i * 16 + 4 * (lane >> 4) + r;
        int row  = mb * 128 + rloc;
        float v = acc[i][j][r];
        if (MODE == 0) {
          C[(size_t)row * Ncol + col] = v;
        } else if (MODE == 1) {
          C[(size_t)row * Ncol + col] += v;
        } else if (MODE == 2) {
          float hv = fmaxf(v + bcol, 0.f);
          ushort a, b2, c2; split3(hv, a, b2, c2);
          size_t pstride = (size_t)8 * 128 * 4096;   // MT_h=8, KT_h=128
          size_t base = (((size_t)(e * 3) * 8 + mb) * 128 + (col >> 5)) * 4096
                        + (size_t)rloc * 32 + (col & 31);
          Ht[base] = a; Ht[base + pstride] = b2; Ht[base + 2 * pstride] = c2;
        } else {
          int tok = selL[rloc];
          if (tok < NTOK)
            atomicAdd(&Xout[(size_t)tok * DD + col], (v + bcol) * gebL[rloc]);
        }
      }
    }
  }
}

// ---------------- attention v2: chunked LDS flash, lane-parallel ----------------
// Block: 4 waves, one (b,h), 16 q-rows. K/V chunks of 64 tokens in LDS.
__global__ __launch_bounds__(256) void attn_kernel2(
    const float* __restrict__ qkv, float* __restrict__ o)
{
  __shared__ float Kt[64][65];     // pitch 65: bank (row+d)%32 -> 2-way, free
  __shared__ float Vt[64][65];
  __shared__ float qT[64][16];     // [d][row], pitch 64B for b128 reads
  __shared__ float pb[4][64][4];   // per-wave [k][row]: b128 broadcast reads

  const int tid = threadIdx.x, lane = tid & 63, wid = tid >> 6;
  const int q0 = blockIdx.x * 16, h = blockIdx.y, b = blockIdx.z;
  const size_t rs = 3 * DD;
  const float* base = qkv + (size_t)(b * TT) * rs + h * HD;

  { // stage Q transposed, pre-scaled by 1/sqrt(HD)=0.125
    int r = tid & 15, c4 = tid >> 4;
    float4 v = *(const float4*)(base + (size_t)(q0 + r) * rs + c4 * 4);
    qT[c4 * 4 + 0][r] = v.x * 0.125f;
    qT[c4 * 4 + 1][r] = v.y * 0.125f;
    qT[c4 * 4 + 2][r] = v.z * 0.125f;
    qT[c4 * 4 + 3][r] = v.w * 0.125f;
  }

  float m[4], lsum[4], oacc[4];
#pragma unroll
  for (int r = 0; r < 4; ++r) { m[r] = -INFINITY; lsum[r] = 0.f; oacc[r] = 0.f; }

  const int kr = tid >> 2, kf = tid & 3;

  for (int c = 0; c < TT / 64; ++c) {
    __syncthreads();   // prev chunk's reads done (and qT visible on c=0)
    { // stage K,V chunk (64 tokens x 64 dims), coalesced 64B groups
      const float* kp = base + (size_t)(c * 64 + kr) * rs + DD;
#pragma unroll
      for (int i = 0; i < 4; ++i) {
        float4 kv = *(const float4*)(kp + (kf + 4 * i) * 4);
        float4 vv = *(const float4*)(kp + DD + (kf + 4 * i) * 4);
        int d0 = (kf + 4 * i) * 4;
        Kt[kr][d0 + 0] = kv.x; Kt[kr][d0 + 1] = kv.y;
        Kt[kr][d0 + 2] = kv.z; Kt[kr][d0 + 3] = kv.w;
        Vt[kr][d0 + 0] = vv.x; Vt[kr][d0 + 1] = vv.y;
        Vt[kr][d0 + 2] = vv.z; Vt[kr][d0 + 3] = vv.w;
      }
    }
    __syncthreads();

    // ---- scores: lane owns token c*64+lane, 4 q-rows per wave ----
    float s0 = 0.f, s1 = 0.f, s2 = 0.f, s3 = 0.f;
#pragma unroll
    for (int d = 0; d < 64; ++d) {
      float kd = Kt[lane][d];
      float4 q4 = *(const float4*)&qT[d][wid * 4];   // wave-uniform b128
      s0 = fmaf(q4.x, kd, s0); s1 = fmaf(q4.y, kd, s1);
      s2 = fmaf(q4.z, kd, s2); s3 = fmaf(q4.w, kd, s3);
    }
    float sv[4] = {s0, s1, s2, s3};
    // ---- online softmax per row ----
#pragma unroll
    for (int r = 0; r < 4; ++r) {
      float mc = sv[r];
#pragma unroll
      for (int off = 32; off; off >>= 1) mc = fmaxf(mc, __shfl_xor(mc, off, 64));
      float mn = fmaxf(m[r], mc);
      float corr = __expf(m[r] - mn);    // c=0: exp(-inf)=0
      float p = __expf(sv[r] - mn);
      lsum[r] = lsum[r] * corr + wred(p);
      oacc[r] *= corr;
      m[r] = mn;
      pb[wid][lane][r] = p;
    }
    // ---- PV: lane owns dim d=lane ----
#pragma unroll 8
    for (int k = 0; k < 64; ++k) {
      float v = Vt[k][lane];
      float4 p4 = *(const float4*)&pb[wid][k][0];    // wave-uniform b128
      oacc[0] = fmaf(p4.x, v, oacc[0]);
      oacc[1] = fmaf(p4.y, v, oacc[1]);
      oacc[2] = fmaf(p4.z, v, oacc[2]);
      oacc[3] = fmaf(p4.w, v, oacc[3]);
    }
  }
#pragma unroll
  for (int r = 0; r < 4; ++r)
    o[(size_t)(b * TT + q0 + wid * 4 + r) * DD + h * HD + lane] = oacc[r] / lsum[r];
}

// ---------------- router ----------------
__global__ __launch_bounds__(256) void router_kernel(
    const float* __restrict__ xln,
    const float* __restrict__ rt_w, const float* __restrict__ rt_b,
    const float* __restrict__ nz_w, const float* __restrict__ nz_b,
    float* __restrict__ rtbuf)
{
  int n = blockIdx.x, tid = threadIdx.x;
  float4 xv = ((const float4*)(xln + (size_t)n * DD))[tid];
  float xs[4] = {xv.x, xv.y, xv.z, xv.w};
  float ar[EE] = {0.f}, an[EE] = {0.f};
  const float* rw = rt_w + (size_t)tid * 4 * EE;
  const float* nw = nz_w + (size_t)tid * 4 * EE;
#pragma unroll
  for (int j = 0; j < 4; ++j)
#pragma unroll
    for (int e2 = 0; e2 < EE; ++e2) {
      ar[e2] = fmaf(xs[j], rw[j * EE + e2], ar[e2]);
      an[e2] = fmaf(xs[j], nw[j * EE + e2], an[e2]);
    }
#pragma unroll
  for (int e2 = 0; e2 < EE; ++e2) { ar[e2] = wred(ar[e2]); an[e2] = wred(an[e2]); }
  __shared__ float sm[4][16];
  int wid = tid >> 6, lane = tid & 63;
  if (lane == 0) {
#pragma unroll
    for (int e2 = 0; e2 < EE; ++e2) { sm[wid][e2] = ar[e2]; sm[wid][8 + e2] = an[e2]; }
  }
  __syncthreads();
  if (tid < 16) {
    float v = sm[0][tid] + sm[1][tid] + sm[2][tid] + sm[3][tid];
    v += (tid < 8) ? rt_b[tid] : nz_b[tid - 8];
    rtbuf[n * 16 + tid] = v;
  }
}

// ---------------- noisy top-2 ----------------
__global__ __launch_bounds__(256) void topk_kernel(
    const float* __restrict__ rtbuf, const float* __restrict__ noise,
    float* __restrict__ gates, int* __restrict__ maskb)
{
  int n = blockIdx.x * 256 + threadIdx.x;
  float nv[EE];
#pragma unroll
  for (int e = 0; e < EE; ++e) {
    float lg = rtbuf[n * 16 + e];
    float pz = rtbuf[n * 16 + 8 + e];
    float sp = fmaxf(pz, 0.f) + log1pf(expf(-fabsf(pz)));
    nv[e] = lg + noise[(size_t)n * EE + e] * sp;
  }
  int i0 = 0; float v0 = nv[0];
#pragma unroll
  for (int e = 1; e < EE; ++e) if (nv[e] > v0) { v0 = nv[e]; i0 = e; }
  int i1 = -1; float v1 = -INFINITY;
#pragma unroll
  for (int e = 0; e < EE; ++e) if (e != i0 && nv[e] > v1) { v1 = nv[e]; i1 = e; }
  float e1 = expf(v1 - v0);
  float g0 = 1.f / (1.f + e1);
  float g1 = e1 / (1.f + e1);
#pragma unroll
  for (int e = 0; e < EE; ++e) gates[(size_t)n * EE + e] = 0.f;
  gates[(size_t)n * EE + i0] = g0;
  gates[(size_t)n * EE + i1] = g1;
  maskb[n] = (1 << i0) | (1 << i1);
}

// ---------------- per-expert capacity scan ----------------
__global__ __launch_bounds__(256) void capacity_kernel(
    const int* __restrict__ maskb, const float* __restrict__ gates,
    int* __restrict__ sel, float* __restrict__ geb)
{
  int e = blockIdx.x, tid = threadIdx.x;
  __shared__ int s[256];
  __shared__ int soff;
  for (int i = tid; i < CAP; i += 256) { sel[e * CAP + i] = NTOK; geb[e * CAP + i] = 0.f; }
  if (tid == 0) soff = 0;
  __syncthreads();
  for (int c = 0; c < NTOK; c += 256) {
    int n = c + tid;
    int m = (maskb[n] >> e) & 1;
    s[tid] = m;
    __syncthreads();
    for (int off = 1; off < 256; off <<= 1) {
      int v = (tid >= off) ? s[tid - off] : 0;
      __syncthreads();
      s[tid] += v;
      __syncthreads();
    }
    int incl = s[tid], tot = s[255];
    int rank = soff + incl - 1;
    if (m && rank < CAP) {
      sel[e * CAP + rank] = n;
      geb[e * CAP + rank] = gates[(size_t)n * EE + e];
    }
    __syncthreads();
    if (tid == 0) soff += tot;
    __syncthreads();
  }
}

// ---------------- launch ----------------
extern "C" void kernel_launch(void* const* d_in, const int* in_sizes, int n_in,
                              void* d_out, int out_size, void* d_ws, size_t ws_size,
                              hipStream_t stream)
{
  (void)in_sizes; (void)n_in; (void)out_size; (void)ws_size;
  const int*   ids   = (const int*)  d_in[0];
  const float* noise = (const float*)d_in[1];
  const float* tok   = (const float*)d_in[2];
  const float* pos   = (const float*)d_in[3];
  const float* ln1g  = (const float*)d_in[4];
  const float* ln1b  = (const float*)d_in[5];
  const float* ln2g  = (const float*)d_in[6];
  const float* ln2b  = (const float*)d_in[7];
  const float* qkvw  = (const float*)d_in[8];
  const float* outw  = (const float*)d_in[9];
  const float* rtw   = (const float*)d_in[10];
  const float* rtb   = (const float*)d_in[11];
  const float* nzw   = (const float*)d_in[12];
  const float* nzb   = (const float*)d_in[13];
  const float* ew1   = (const float*)d_in[14];
  const float* eb1   = (const float*)d_in[15];
  const float* ew2   = (const float*)d_in[16];
  const float* eb2   = (const float*)d_in[17];
  const float* lnfg  = (const float*)d_in[18];
  const float* lnfb  = (const float*)d_in[19];
  float* outp = (float*)d_out;

  size_t off = 0;
  auto alloc = [&](size_t bytes) {
    char* p = (char*)d_ws + off;
    off = (off + bytes + 255) & ~(size_t)255;
    return p;
  };
  float*  x      = (float*) alloc((size_t)NTOK * DD * 4);
  float*  xln    = (float*) alloc((size_t)NTOK * DD * 4);
  float*  obuf   = (float*) alloc((size_t)NTOK * DD * 4);
  float*  qkvbuf = (float*) alloc((size_t)NTOK * 3 * DD * 4);
  ushort* AT     = (ushort*)alloc((size_t)EE * 3 * 8 * 32 * 4096 * 2);
  ushort* WT     = (ushort*)alloc((size_t)EE * 3 * 32 * 32 * 4096 * 2);
  ushort* hT     = (ushort*)alloc((size_t)EE * 3 * 8 * 128 * 4096 * 2);
  float*  rtbuf  = (float*) alloc((size_t)NTOK * 16 * 4);
  float*  gates  = (float*) alloc((size_t)NTOK * EE * 4);
  float*  geb    = (float*) alloc((size_t)EE * CAP * 4);
  int*    sel    = (int*)   alloc((size_t)EE * CAP * 4);
  int*    maskb  = (int*)   alloc((size_t)NTOK * 4);

  embed_kernel<<<NTOK, 256, 0, stream>>>(ids, tok, pos, x);

  for (int l = 0; l < LL; ++l) {
    ln_kernel<<<NTOK, 256, 0, stream>>>(x, ln1g + l * DD, ln1b + l * DD, xln);

    // QKV = xln @ qkv_w[l]
    convert_a<<<dim3(32, 32, 1), 256, 0, stream>>>(xln, AT, DD, 32, 32, nullptr, 0);
    convert_w<<<dim3(24, 32, 1), 256, 0, stream>>>(qkvw + (size_t)l * DD * 3 * DD, WT,
                                                   3 * DD, 24, 32, 0);
    gemm3<0><<<dim3(24, 32, 1), 256, 0, stream>>>(AT, WT, qkvbuf, 3 * DD, 32, 32, 24,
                                                  nullptr, 0, nullptr, nullptr, nullptr, nullptr);

    attn_kernel2<<<dim3(TT / 16, HH, BD), 256, 0, stream>>>(qkvbuf, obuf);

    // x += obuf @ out_w[l]
    convert_a<<<dim3(32, 32, 1), 256, 0, stream>>>(obuf, AT, DD, 32, 32, nullptr, 0);
    convert_w<<<dim3(8, 32, 1), 256, 0, stream>>>(outw + (size_t)l * DD * DD, WT,
                                                  DD, 8, 32, 0);
    gemm3<1><<<dim3(8, 32, 1), 256, 0, stream>>>(AT, WT, x, DD, 32, 32, 8,
                                                 nullptr, 0, nullptr, nullptr, nullptr, nullptr);

    ln_kernel<<<NTOK, 256, 0, stream>>>(x, ln2g + l * DD, ln2b + l * DD, xln);

    router_kernel<<<NTOK, 256, 0, stream>>>(
        xln, rtw + (size_t)l * DD * EE, rtb + l * EE,
        nzw + (size_t)l * DD * EE, nzb + l * EE, rtbuf);
    topk_kernel<<<NTOK / 256, 256, 0, stream>>>(
        rtbuf, noise + (size_t)l * NTOK * EE, gates, maskb);
    capacity_kernel<<<EE, 256, 0, stream>>>(maskb, gates, sel, geb);

    // h = relu(xe @ w1 + b1), tiled bf16x3 output
    convert_a<<<dim3(8, 32, EE), 256, 0, stream>>>(xln, AT, DD, 8, 32, sel, 1);
    convert_w<<<dim3(32, 32, EE), 256, 0, stream>>>(ew1 + (size_t)l * EE * DD * DFF, WT,
                                                    DFF, 32, 32, (long)DD * DFF);
    gemm3<2><<<dim3(32, 8, EE), 256, 0, stream>>>(AT, WT, nullptr, DFF, 32, 8, 32,
                                                  eb1 + (size_t)l * EE * DFF, DFF,
                                                  nullptr, nullptr, nullptr, hT);

    // x[sel] += (h @ w2 + b2) * gate
    convert_w<<<dim3(8, 128, EE), 256, 0, stream>>>(ew2 + (size_t)l * EE * DFF * DD, WT,
                                                    DD, 8, 128, (long)DFF * DD);
    gemm3<3><<<dim3(8, 8, EE), 256, 0, stream>>>(hT, WT, nullptr, DD, 128, 8, 8,
                                                 eb2 + (size_t)l * EE * DD, DD,
                                                 sel, geb, x, nullptr);
  }

  ln_kernel<<<NTOK, 256, 0, stream>>>(x, lnfg, lnfb, outp);
}